// Round 1
// baseline (434.869 us; speedup 1.0000x reference)
//
#include <hip/hip_runtime.h>
#include <math.h>

// Problem constants (fixed by reference)
#define BS_TOT 32768      // B*S = 16*2048
#define IN_DIM 768
#define G_N 2
#define V_N 320
#define D_N 384
#define OUT_N 768
#define EPS_F 1e-10f

// logits GEMM tiling
#define BM 64
#define BK 32
#define APAD 4
#define ASTRIDE (BM + APAD)   // 68 floats; keeps b128 reads 16B-aligned

#define GLOBAL_LOAD_LDS16(gaddr, laddr)                                        \
  __builtin_amdgcn_global_load_lds(                                            \
      (const __attribute__((address_space(1))) unsigned int*)(gaddr),          \
      (__attribute__((address_space(3))) unsigned int*)(laddr), 16, 0, 0)

// ---------------------------------------------------------------------------
// Kernel A: P[g*320+v][o] = sum_d codebooks[g][v][d] * W_out[g*384+d][o]
// 640x768 output, 0.38 GFLOP. Grid (3, 80), block 256.
// ---------------------------------------------------------------------------
__global__ __launch_bounds__(256) void precompute_P(
    const float* __restrict__ cb, const float* __restrict__ Wo,
    float* __restrict__ P)
{
    const int tid = threadIdx.x;
    const int c0  = blockIdx.x * 256;   // output-col tile
    const int r0  = blockIdx.y * 8;     // 8 flat (g,v) rows; 320%8==0 so g uniform
    const int g   = r0 / V_N;
    __shared__ float As[8][D_N];        // 12 KB
    // stage 8 codebook rows (contiguous in [G,V,D] flat layout)
    {
        const float4* src = (const float4*)(cb + (size_t)r0 * D_N);
        float4* dst = (float4*)(&As[0][0]);
        #pragma unroll
        for (int p = 0; p < 3; ++p) dst[tid + p * 256] = src[tid + p * 256];
    }
    __syncthreads();
    float acc[8];
    #pragma unroll
    for (int i = 0; i < 8; ++i) acc[i] = 0.f;
    const float* wp = Wo + ((size_t)g * D_N) * OUT_N + c0 + tid;
    for (int d = 0; d < D_N; d += 4) {
        float w0 = wp[(size_t)(d + 0) * OUT_N];
        float w1 = wp[(size_t)(d + 1) * OUT_N];
        float w2 = wp[(size_t)(d + 2) * OUT_N];
        float w3 = wp[(size_t)(d + 3) * OUT_N];
        #pragma unroll
        for (int i = 0; i < 8; ++i) {
            float4 a = *(const float4*)&As[i][d];   // wave-uniform broadcast
            acc[i] = fmaf(a.x, w0, acc[i]);
            acc[i] = fmaf(a.y, w1, acc[i]);
            acc[i] = fmaf(a.z, w2, acc[i]);
            acc[i] = fmaf(a.w, w3, acc[i]);
        }
    }
    #pragma unroll
    for (int i = 0; i < 8; ++i)
        P[(size_t)(r0 + i) * OUT_N + c0 + tid] = acc[i];
}

// ---------------------------------------------------------------------------
// Kernel B: fused logits GEMM + gumbel + argmax.
// M = 32768 rows (bs), grid.y = g. BM=64, N=320 (full), K=384 in 12 BK=32 tiles.
// Thread tile 8 rows x 10 cols = 80 fp32 accumulators; 256 thr = 8(mt) x 32(nt).
// ---------------------------------------------------------------------------
__global__ __launch_bounds__(256, 2) void logits_argmax(
    const float* __restrict__ z, const float* __restrict__ noise,
    const float* __restrict__ Wl, const float* __restrict__ bl,
    int* __restrict__ idx)
{
    const int tid = threadIdx.x;
    const int g   = blockIdx.y;
    const int m0  = blockIdx.x * BM;
    const int nt  = tid & 31;     // v-tile lane: cols nt*10 .. nt*10+9
    const int mt  = tid >> 5;     // row group: rows mt*8 .. mt*8+7

    __shared__ float As[BK][ASTRIDE];   // [k][m], 8.7 KB
    __shared__ float Bs[BK * V_N];      // [k][v] flat, 40 KB (contiguous for async)

    float acc[8][10];
    #pragma unroll
    for (int i = 0; i < 8; ++i)
        #pragma unroll
        for (int j = 0; j < 10; ++j) acc[i][j] = 0.f;

    // A staging map: thread t loads z[m0 + t/8][g*384 + kt*32 + (t%8)*4 ..+3]
    const int a_m = tid >> 3;           // 0..31 (second pass: +32)
    const int a_k = (tid & 7) << 2;     // 0,4,...,28
    const float* zbase = z + (size_t)(m0 + a_m) * IN_DIM + g * D_N + a_k;

    const float4* Wl4 = (const float4*)Wl;   // B-tile kt is contiguous: 2560 f4
    float4* Bs4 = (float4*)Bs;
    const int wv = tid >> 6;            // wave id 0..3
    const int ln = tid & 63;            // lane

    float4 apf0 = *(const float4*)(zbase);
    float4 apf1 = *(const float4*)(zbase + 32 * IN_DIM);

    for (int kt = 0; kt < 12; ++kt) {
        __syncthreads();   // prior tile fully consumed
        // async stage W_logits tile (32x320 = 2560 f4): 4 waves x 10 chunks x 64 lanes
        #pragma unroll
        for (int p = 0; p < 10; ++p) {
            GLOBAL_LOAD_LDS16(Wl4 + (size_t)kt * 2560 + wv * 640 + p * 64 + ln,
                              Bs4 + wv * 640 + p * 64);
        }
        // write prefetched A regs to transposed LDS
        {
            int m = a_m;
            As[a_k + 0][m] = apf0.x; As[a_k + 1][m] = apf0.y;
            As[a_k + 2][m] = apf0.z; As[a_k + 3][m] = apf0.w;
            m = a_m + 32;
            As[a_k + 0][m] = apf1.x; As[a_k + 1][m] = apf1.y;
            As[a_k + 2][m] = apf1.z; As[a_k + 3][m] = apf1.w;
        }
        __syncthreads();   // drains vmcnt -> B tile resident; A writes visible
        if (kt < 11) {     // prefetch next A tile during compute
            apf0 = *(const float4*)(zbase + (kt + 1) * BK);
            apf1 = *(const float4*)(zbase + (kt + 1) * BK + 32 * IN_DIM);
        }
        #pragma unroll 4
        for (int k = 0; k < BK; ++k) {
            float4 a0 = *(const float4*)&As[k][mt * 8];
            float4 a1 = *(const float4*)&As[k][mt * 8 + 4];
            float b[10];
            const float* brow = &Bs[k * V_N + nt * 10];
            #pragma unroll
            for (int c = 0; c < 5; ++c) {
                float2 t = *(const float2*)&brow[2 * c];
                b[2 * c] = t.x; b[2 * c + 1] = t.y;
            }
            float a[8] = {a0.x, a0.y, a0.z, a0.w, a1.x, a1.y, a1.z, a1.w};
            #pragma unroll
            for (int i = 0; i < 8; ++i)
                #pragma unroll
                for (int j = 0; j < 10; ++j)
                    acc[i][j] = fmaf(a[i], b[j], acc[i][j]);
        }
    }

    // ---- epilogue: + b_logits + gumbel, per-row argmax ----
    float blv[10];
    #pragma unroll
    for (int c = 0; c < 5; ++c) {
        float2 t = *(const float2*)&bl[nt * 10 + 2 * c];
        blv[2 * c] = t.x; blv[2 * c + 1] = t.y;
    }
    #pragma unroll
    for (int i = 0; i < 8; ++i) {
        const int row = m0 + mt * 8 + i;   // flat bs index
        const float* nrow = noise + ((size_t)row * G_N + g) * V_N + nt * 10;
        float best = -INFINITY; int bi = 0;
        #pragma unroll
        for (int c = 0; c < 5; ++c) {
            float2 nn = *(const float2*)&nrow[2 * c];
            float l0 = acc[i][2 * c]     + blv[2 * c]
                       - logf(-logf(nn.x + EPS_F) + EPS_F);
            float l1 = acc[i][2 * c + 1] + blv[2 * c + 1]
                       - logf(-logf(nn.y + EPS_F) + EPS_F);
            if (l0 > best) { best = l0; bi = nt * 10 + 2 * c; }
            if (l1 > best) { best = l1; bi = nt * 10 + 2 * c + 1; }
        }
        // reduce across the 32 nt-lanes (stay within 32-lane halves of the wave)
        #pragma unroll
        for (int off = 1; off < 32; off <<= 1) {
            float ov = __shfl_xor(best, off, 64);
            int   oi = __shfl_xor(bi,   off, 64);
            if (ov > best || (ov == best && oi < bi)) { best = ov; bi = oi; }
        }
        if (nt == 0) idx[(size_t)row * G_N + g] = bi;
    }
}

// ---------------------------------------------------------------------------
// Kernel C: out[row] = P[idx0[row]] + P[320 + idx1[row]] + b_out
// 4 rows per block (768 f4 = 3 f4/thread). Write-bound: 96 MiB.
// ---------------------------------------------------------------------------
__global__ __launch_bounds__(256) void gather_out(
    const float* __restrict__ P, const int* __restrict__ idx,
    const float* __restrict__ bo, float* __restrict__ out)
{
    const int tid  = threadIdx.x;
    const int row0 = blockIdx.x << 2;
    #pragma unroll
    for (int p = 0; p < 3; ++p) {
        int f   = tid + (p << 8);       // 0..767
        int rl  = f / 192;
        int c4  = f - rl * 192;
        int row = row0 + rl;
        int i0  = idx[row * 2];
        int i1  = idx[row * 2 + 1];
        float4 a  = ((const float4*)(P + (size_t)i0 * OUT_N))[c4];
        float4 b2 = ((const float4*)(P + (size_t)(V_N + i1) * OUT_N))[c4];
        float4 c  = ((const float4*)bo)[c4];
        float4 r;
        r.x = a.x + b2.x + c.x;
        r.y = a.y + b2.y + c.y;
        r.z = a.z + b2.z + c.z;
        r.w = a.w + b2.w + c.w;
        ((float4*)(out + (size_t)row * OUT_N))[c4] = r;
    }
}

// ---------------------------------------------------------------------------
extern "C" void kernel_launch(void* const* d_in, const int* in_sizes, int n_in,
                              void* d_out, int out_size, void* d_ws, size_t ws_size,
                              hipStream_t stream)
{
    const float* z     = (const float*)d_in[0];
    const float* noise = (const float*)d_in[1];
    const float* Wl    = (const float*)d_in[2];
    const float* bl    = (const float*)d_in[3];
    const float* cb    = (const float*)d_in[4];
    const float* Wo    = (const float*)d_in[5];
    const float* bo    = (const float*)d_in[6];
    float* out = (float*)d_out;

    // workspace: P (640*768 f32 = 1,966,080 B) then idx (32768*2 int = 262,144 B)
    float* P  = (float*)d_ws;
    int* idx  = (int*)((char*)d_ws + (size_t)(G_N * V_N) * OUT_N * sizeof(float));

    dim3 gA(OUT_N / 256, (G_N * V_N) / 8);
    precompute_P<<<gA, 256, 0, stream>>>(cb, Wo, P);

    dim3 gB(BS_TOT / BM, G_N);
    logits_argmax<<<gB, 256, 0, stream>>>(z, noise, Wl, bl, idx);

    gather_out<<<BS_TOT / 4, 256, 0, stream>>>(P, idx, bo, out);
}

// Round 2
// 338.506 us; speedup vs baseline: 1.2847x; 1.2847x over previous
//
#include <hip/hip_runtime.h>
#include <math.h>

// Problem constants (fixed by reference)
#define BS_TOT 32768      // B*S = 16*2048
#define IN_DIM 768
#define G_N 2
#define V_N 320
#define D_N 384
#define OUT_N 768
#define EPS_F 1e-10f

typedef _Float16 f16x8 __attribute__((ext_vector_type(8)));
typedef float    f32x16 __attribute__((ext_vector_type(16)));

#define GLOBAL_LOAD_LDS16(gaddr, laddr)                                        \
  __builtin_amdgcn_global_load_lds(                                            \
      (const __attribute__((address_space(1))) unsigned int*)(gaddr),          \
      (__attribute__((address_space(3))) unsigned int*)(laddr), 16, 0, 0)

// ---------------------------------------------------------------------------
// Kernel 0: split W_logits [384][320] fp32 into two f16 planes, tile-ordered
// for direct global_load_lds staging: Wp[(kt*2+p)*4+kh][v][j] f16, where
// k = kt*32 + kh*8 + j. Plane 1 = f16(w); plane 2 = f16(4096*(w - plane1)).
// ---------------------------------------------------------------------------
__global__ __launch_bounds__(256) void prep_w(
    const float* __restrict__ Wl, _Float16* __restrict__ Wp)
{
    int e = blockIdx.x * 256 + threadIdx.x;
    if (e >= D_N * V_N) return;
    int k = e / V_N, v = e - k * V_N;
    int kt = k >> 5, kl = k & 31, kh = kl >> 3, j = kl & 7;
    float w = Wl[e];
    _Float16 a = (_Float16)w;
    float r = (w - (float)a) * 4096.f;
    Wp[((size_t)((kt * 2 + 0) * 4 + kh) * V_N + v) * 8 + j] = a;
    Wp[((size_t)((kt * 2 + 1) * 4 + kh) * V_N + v) * 8 + j] = (_Float16)r;
}

// ---------------------------------------------------------------------------
// Kernel A: P[g*320+v][o] = sum_d codebooks[g][v][d] * W_out[g*384+d][o]
// (unchanged from R1 — validated)
// ---------------------------------------------------------------------------
__global__ __launch_bounds__(256) void precompute_P(
    const float* __restrict__ cb, const float* __restrict__ Wo,
    float* __restrict__ P)
{
    const int tid = threadIdx.x;
    const int c0  = blockIdx.x * 256;
    const int r0  = blockIdx.y * 8;
    const int g   = r0 / V_N;
    __shared__ float As[8][D_N];
    {
        const float4* src = (const float4*)(cb + (size_t)r0 * D_N);
        float4* dst = (float4*)(&As[0][0]);
        #pragma unroll
        for (int p = 0; p < 3; ++p) dst[tid + p * 256] = src[tid + p * 256];
    }
    __syncthreads();
    float acc[8];
    #pragma unroll
    for (int i = 0; i < 8; ++i) acc[i] = 0.f;
    const float* wp = Wo + ((size_t)g * D_N) * OUT_N + c0 + tid;
    for (int d = 0; d < D_N; d += 4) {
        float w0 = wp[(size_t)(d + 0) * OUT_N];
        float w1 = wp[(size_t)(d + 1) * OUT_N];
        float w2 = wp[(size_t)(d + 2) * OUT_N];
        float w3 = wp[(size_t)(d + 3) * OUT_N];
        #pragma unroll
        for (int i = 0; i < 8; ++i) {
            float4 a = *(const float4*)&As[i][d];
            acc[i] = fmaf(a.x, w0, acc[i]);
            acc[i] = fmaf(a.y, w1, acc[i]);
            acc[i] = fmaf(a.z, w2, acc[i]);
            acc[i] = fmaf(a.w, w3, acc[i]);
        }
    }
    #pragma unroll
    for (int i = 0; i < 8; ++i)
        P[(size_t)(r0 + i) * OUT_N + c0 + tid] = acc[i];
}

// ---------------------------------------------------------------------------
// Kernel B: split-f16 MFMA logits GEMM + gumbel + argmax.
// Per g: M=32768, N=320, K=384. BM=64, block 256 (2 M-waves x 2 N-waves),
// wave tile 32x160: 5 N-frags of 32x32, two acc sets (main + 2^-12 * cross).
// A (z) split to f16 planes on the fly; B staged from pre-split Wp via
// global_load_lds. LDS layouts give 16B-per-lane stride (conflict-free b128).
// ---------------------------------------------------------------------------
__global__ __launch_bounds__(256, 2) void logits_mfma(
    const float* __restrict__ z, const float* __restrict__ noise,
    const f16x8* __restrict__ Wp, const float* __restrict__ bl,
    int* __restrict__ idx)
{
    const int tid  = threadIdx.x;
    const int g    = blockIdx.y;
    const int m0   = blockIdx.x * 64;
    const int ln   = tid & 63;
    const int wv   = tid >> 6;
    const int wrow = wv >> 1;      // 0..1: M half
    const int wcol = wv & 1;       // 0..1: N half (160 cols)
    const int lh   = ln >> 5;
    const int l5   = ln & 31;

    __shared__ f16x8 BsV[2560];    // [plane][kh][col] in 16B units, 40960 B
    __shared__ f16x8 AsV[512];     // [plane][kh][row], 8192 B
    __shared__ float sVal[2][64];
    __shared__ int   sIdx[2][64];

    f32x16 accM[5], accC[5];
    #pragma unroll
    for (int nf = 0; nf < 5; ++nf)
        #pragma unroll
        for (int i = 0; i < 16; ++i) { accM[nf][i] = 0.f; accC[nf][i] = 0.f; }

    // A staging map: thread stages row (tid&63), kh = tid>>6 (8 consecutive k)
    const int arow_s = tid & 63;
    const int akh    = tid >> 6;
    const float* zrow = z + (size_t)(m0 + arow_s) * IN_DIM + g * D_N + akh * 8;

    float4 ap0 = *(const float4*)(zrow);
    float4 ap1 = *(const float4*)(zrow + 4);

    const int arow = wrow * 32 + l5;   // fragment row in block
    const int bcol = wcol * 160 + l5;  // fragment col base in block

    for (int kt = 0; kt < 12; ++kt) {
        __syncthreads();
        // stage B tile (40960 B = 2560 x 16B): wave-uniform base + lane*16
        #pragma unroll
        for (int p = 0; p < 10; ++p) {
            GLOBAL_LOAD_LDS16(Wp + (size_t)kt * 2560 + wv * 640 + p * 64 + ln,
                              BsV + wv * 640 + p * 64);
        }
        // split prefetched A regs into two f16 planes, write to LDS
        {
            float x[8] = {ap0.x, ap0.y, ap0.z, ap0.w, ap1.x, ap1.y, ap1.z, ap1.w};
            f16x8 h1, h2;
            #pragma unroll
            for (int i = 0; i < 8; ++i) {
                _Float16 a = (_Float16)x[i];
                float r = (x[i] - (float)a) * 4096.f;
                h1[i] = a;
                h2[i] = (_Float16)r;
            }
            AsV[(0 * 4 + akh) * 64 + arow_s] = h1;
            AsV[(1 * 4 + akh) * 64 + arow_s] = h2;
        }
        __syncthreads();   // drains vmcnt (B resident) + A writes visible
        if (kt < 11) {     // prefetch next A tile
            ap0 = *(const float4*)(zrow + (kt + 1) * 32);
            ap1 = *(const float4*)(zrow + (kt + 1) * 32 + 4);
        }
        #pragma unroll
        for (int b = 0; b < 2; ++b) {
            // k_local = (b*2+lh)*8 + j
            f16x8 a0 = AsV[(0 * 4 + b * 2 + lh) * 64 + arow];
            f16x8 a1 = AsV[(1 * 4 + b * 2 + lh) * 64 + arow];
            #pragma unroll
            for (int nf = 0; nf < 5; ++nf) {
                f16x8 b0 = BsV[(0 * 4 + b * 2 + lh) * 320 + bcol + nf * 32];
                f16x8 b1 = BsV[(1 * 4 + b * 2 + lh) * 320 + bcol + nf * 32];
                accM[nf] = __builtin_amdgcn_mfma_f32_32x32x16_f16(a0, b0, accM[nf], 0, 0, 0);
                accC[nf] = __builtin_amdgcn_mfma_f32_32x32x16_f16(a0, b1, accC[nf], 0, 0, 0);
                accC[nf] = __builtin_amdgcn_mfma_f32_32x32x16_f16(a1, b0, accC[nf], 0, 0, 0);
            }
        }
    }

    // ---- epilogue: logits = main + 2^-12*cross + bl + gumbel; argmax ----
    float blv[5];
    #pragma unroll
    for (int nf = 0; nf < 5; ++nf) blv[nf] = bl[wcol * 160 + nf * 32 + l5];

    #pragma unroll
    for (int r = 0; r < 16; ++r) {
        const int rowloc = (r & 3) + 8 * (r >> 2) + 4 * lh;   // C/D row map (m74/m101)
        const int grow   = m0 + wrow * 32 + rowloc;
        const float* np_ = noise + ((size_t)grow * G_N + g) * V_N + wcol * 160 + l5;
        float best = -INFINITY; int bi = 0;
        #pragma unroll
        for (int nf = 0; nf < 5; ++nf) {
            float u   = np_[nf * 32];
            float gum = -__logf(-__logf(u + EPS_F) + EPS_F);
            float v   = accM[nf][r] + 2.44140625e-4f * accC[nf][r] + blv[nf] + gum;
            int   c   = wcol * 160 + nf * 32 + l5;
            if (v > best) { best = v; bi = c; }
        }
        #pragma unroll
        for (int off = 1; off < 32; off <<= 1) {   // reduce within 32-lane half
            float ov = __shfl_xor(best, off);
            int   oi = __shfl_xor(bi, off);
            if (ov > best || (ov == best && oi < bi)) { best = ov; bi = oi; }
        }
        if (l5 == 0) {
            sVal[wcol][wrow * 32 + rowloc] = best;
            sIdx[wcol][wrow * 32 + rowloc] = bi;
        }
    }
    __syncthreads();
    if (tid < 64) {
        float v0 = sVal[0][tid], v1 = sVal[1][tid];
        int   i0 = sIdx[0][tid], i1 = sIdx[1][tid];
        int   b  = (v1 > v0 || (v1 == v0 && i1 < i0)) ? i1 : i0;
        idx[(size_t)(m0 + tid) * G_N + g] = b;
    }
}

// ---------------------------------------------------------------------------
// Kernel C: out[row] = P[idx0[row]] + P[320 + idx1[row]] + b_out
// (unchanged from R1 — validated, write-bound)
// ---------------------------------------------------------------------------
__global__ __launch_bounds__(256) void gather_out(
    const float* __restrict__ P, const int* __restrict__ idx,
    const float* __restrict__ bo, float* __restrict__ out)
{
    const int tid  = threadIdx.x;
    const int row0 = blockIdx.x << 2;
    #pragma unroll
    for (int p = 0; p < 3; ++p) {
        int f   = tid + (p << 8);
        int rl  = f / 192;
        int c4  = f - rl * 192;
        int row = row0 + rl;
        int i0  = idx[row * 2];
        int i1  = idx[row * 2 + 1];
        float4 a  = ((const float4*)(P + (size_t)i0 * OUT_N))[c4];
        float4 b2 = ((const float4*)(P + (size_t)(V_N + i1) * OUT_N))[c4];
        float4 c  = ((const float4*)bo)[c4];
        float4 r;
        r.x = a.x + b2.x + c.x;
        r.y = a.y + b2.y + c.y;
        r.z = a.z + b2.z + c.z;
        r.w = a.w + b2.w + c.w;
        ((float4*)(out + (size_t)row * OUT_N))[c4] = r;
    }
}

// ---------------------------------------------------------------------------
extern "C" void kernel_launch(void* const* d_in, const int* in_sizes, int n_in,
                              void* d_out, int out_size, void* d_ws, size_t ws_size,
                              hipStream_t stream)
{
    const float* z     = (const float*)d_in[0];
    const float* noise = (const float*)d_in[1];
    const float* Wl    = (const float*)d_in[2];
    const float* bl    = (const float*)d_in[3];
    const float* cb    = (const float*)d_in[4];
    const float* Wo    = (const float*)d_in[5];
    const float* bo    = (const float*)d_in[6];
    float* out = (float*)d_out;

    // ws layout: P (1,966,080 B) | idx (262,144 B) | Wp f16 planes (491,520 B)
    float*     P   = (float*)d_ws;
    int*       idx = (int*)((char*)d_ws + 1966080);
    _Float16*  Wp  = (_Float16*)((char*)d_ws + 2228224);

    prep_w<<<(D_N * V_N + 255) / 256, 256, 0, stream>>>(Wl, Wp);

    dim3 gA(OUT_N / 256, (G_N * V_N) / 8);
    precompute_P<<<gA, 256, 0, stream>>>(cb, Wo, P);

    dim3 gB(BS_TOT / 64, G_N);
    logits_mfma<<<gB, 256, 0, stream>>>(z, noise, (const f16x8*)Wp, bl, idx);

    gather_out<<<BS_TOT / 4, 256, 0, stream>>>(P, idx, bo, out);
}